// Round 7
// baseline (448.806 us; speedup 1.0000x reference)
//
#include <hip/hip_runtime.h>
#include <stdint.h>

#define DEV static __device__ __forceinline__

typedef unsigned short u16;
typedef u16  u16x8 __attribute__((ext_vector_type(8)));
typedef u16  u16x4 __attribute__((ext_vector_type(4)));
typedef float f32x4 __attribute__((ext_vector_type(4)));
typedef short s16x8 __attribute__((ext_vector_type(8)));   // 8 bf16 as shorts

// problem dims
#define BB 16
#define CC 1024
#define SS 1024      // Sq = 32*32
#define CTX 2048
#define SKK 256
#define NH 16
#define HD 64
#define NG 32
#define ATT_SCALE 0.35355339059327373f   // 1/64^0.25

DEV u16 f2bf(float f) {                    // fp32 -> bf16 RNE
  uint32_t u = __float_as_uint(f);
  return (u16)((u + 0x7fffu + ((u >> 16) & 1u)) >> 16);
}
DEV s16x8 ld8(const u16* p) { return __builtin_bit_cast(s16x8, *(const u16x8*)p); }
DEV f32x4 zero4() { f32x4 z = {0.f, 0.f, 0.f, 0.f}; return z; }

// async global->LDS, 16B per lane. LDS dst is wave-uniform base + lane*16.
DEV void gload_lds16(const void* g, const void* l) {
  __builtin_amdgcn_global_load_lds(
      (const __attribute__((address_space(1))) unsigned int*)(uintptr_t)g,
      (__attribute__((address_space(3))) unsigned int*)(uint32_t)(uintptr_t)l,
      16, 0, 0);
}

// ---------------- prep: weights fp32->bf16 (3 tensors) + mask bias ----------------
__global__ __launch_bounds__(256) void prep_misc(const float* __restrict__ Wq,
                                                 const float* __restrict__ Wkv,
                                                 const float* __restrict__ Wp,
                                                 const int* __restrict__ mask,
                                                 u16* __restrict__ wq_bf,
                                                 u16* __restrict__ wkv_bf,
                                                 u16* __restrict__ wp_bf,
                                                 float* __restrict__ mb) {
  const int bid = blockIdx.x, tid = threadIdx.x;
  const float* src; u16* dst; int i;
  if (bid < 1024)      { src = Wq;  dst = wq_bf;  i = bid * 256 + tid; }
  else if (bid < 5120) { src = Wkv; dst = wkv_bf; i = (bid - 1024) * 256 + tid; }
  else if (bid < 6144) { src = Wp;  dst = wp_bf;  i = (bid - 5120) * 256 + tid; }
  else {
    int j = (bid - 6144) * 256 + tid;
    mb[j] = mask[j] ? 0.f : -1e9f;
    return;
  }
  f32x4 v = ((const f32x4*)src)[i];
  u16x4 o; o[0]=f2bf(v[0]); o[1]=f2bf(v[1]); o[2]=f2bf(v[2]); o[3]=f2bf(v[3]);
  ((u16x4*)dst)[i] = o;
}

// ---------------- GroupNorm stats (x: blocks 0..511, ctx: 512..1023) ----
__global__ __launch_bounds__(256) void gn_stats_all(const float* __restrict__ x,
                                                    const float* __restrict__ ctx,
                                                    float* __restrict__ stx,
                                                    float* __restrict__ stc) {
  const int bid = blockIdx.x, tid = threadIdx.x;
  float s = 0.f, ss = 0.f;
  float* st; int slot; float inv_n;
  if (bid < 512) {
    const int b = bid >> 5, g = bid & 31;
    const float* p = x + ((size_t)b * CC + g * 32) * SS;
    for (int it = 0; it < 32; ++it) {
      f32x4 v = *(const f32x4*)(p + it * 1024 + tid * 4);
      s  += v[0] + v[1] + v[2] + v[3];
      ss += v[0]*v[0] + v[1]*v[1] + v[2]*v[2] + v[3]*v[3];
    }
    st = stx; slot = bid; inv_n = 1.f / 32768.f;
  } else {
    const int bid2 = bid - 512;
    const int b = bid2 >> 5, g = bid2 & 31;
    const float* p = ctx + (size_t)b * SKK * CTX + g * 64;
    const int ch = tid & 63, r0 = tid >> 6;
    for (int it = 0; it < 64; ++it) {
      float v = p[(size_t)(it * 4 + r0) * CTX + ch];
      s += v; ss += v * v;
    }
    st = stc; slot = bid2; inv_n = 1.f / 16384.f;
  }
  __shared__ float red[512];
  red[tid] = s; red[256 + tid] = ss;
  __syncthreads();
  for (int o = 128; o > 0; o >>= 1) {
    if (tid < o) { red[tid] += red[tid + o]; red[256 + tid] += red[256 + tid + o]; }
    __syncthreads();
  }
  if (tid == 0) {
    float mean = red[0] * inv_n;
    float var  = red[256] * inv_n - mean * mean;
    st[slot * 2 + 0] = mean;
    st[slot * 2 + 1] = rsqrtf(var + 1e-5f);
  }
}

// ---------------- GroupNorm apply (ctx: blocks 0..8191; x-transpose: 8192..) --
__global__ __launch_bounds__(256) void gn_apply_all(const float* __restrict__ x,
                                                    const float* __restrict__ ctx,
                                                    const float* __restrict__ stx,
                                                    const float* __restrict__ stc,
                                                    const float* __restrict__ gamma_x,
                                                    const float* __restrict__ beta_x,
                                                    const float* __restrict__ gamma_c,
                                                    const float* __restrict__ beta_c,
                                                    u16* __restrict__ xnT,
                                                    u16* __restrict__ ctxn) {
  __shared__ float t[64][65];
  const int bid = blockIdx.x, tid = threadIdx.x;
  if (bid < 8192) {
    size_t i = ((size_t)bid * 256 + tid) * 4;
    int ch = (int)(i & 2047);
    int bs = (int)(i >> 11);
    int b = bs >> 8;
    int g = ch >> 6;
    float mean = stc[(b * 32 + g) * 2], rstd = stc[(b * 32 + g) * 2 + 1];
    f32x4 v  = *(const f32x4*)(ctx + i);
    f32x4 ga = *(const f32x4*)(gamma_c + ch);
    f32x4 be = *(const f32x4*)(beta_c + ch);
    u16x4 o;
    o[0] = f2bf((v[0] - mean) * rstd * ga[0] + be[0]);
    o[1] = f2bf((v[1] - mean) * rstd * ga[1] + be[1]);
    o[2] = f2bf((v[2] - mean) * rstd * ga[2] + be[2]);
    o[3] = f2bf((v[3] - mean) * rstd * ga[3] + be[3]);
    *(u16x4*)(ctxn + i) = o;
    return;
  }
  const int id2 = bid - 8192;                       // [0, 4096)
  const int b = id2 >> 8, c0 = ((id2 >> 4) & 15) * 64, s0 = (id2 & 15) * 64;
  const int j = tid & 63, i0 = tid >> 6;
  for (int it = 0; it < 16; ++it) {
    int i = it * 4 + i0;
    int c = c0 + i;
    int g = c >> 5;
    float mean = stx[(b * 32 + g) * 2], rstd = stx[(b * 32 + g) * 2 + 1];
    float v = x[((size_t)b * CC + c) * SS + s0 + j];
    t[i][j] = (v - mean) * rstd * gamma_x[c] + beta_x[c];
  }
  __syncthreads();
  for (int it = 0; it < 16; ++it) {
    int jj = it * 4 + i0;
    xnT[((size_t)b * SS + s0 + jj) * CC + c0 + j] = f2bf(t[j][jj]);
  }
}

// ---------------- GEMM core: 128x128 tile, BK=32, 2-phase double-buffered
// pipeline (prefetch next K-tile during MFMA of current), chunk-XOR-swizzled
// LDS via pre-swizzled global source (LDS dest linear per gload_lds rules).
// lds layout: buf{0,1} of 8192 u16: A tile [128 rows][32 k] then B tile.
DEV void gemm_core(const u16* __restrict__ Ab, const u16* __restrict__ Bb,
                   int K, int ld, u16* lds, f32x4 acc[4][4], int wid, int lane) {
  const int wm = wid >> 1, wn = wid & 1;
  const int fr = lane & 15, hi = lane >> 4;
  const int r0 = lane >> 2, c4 = lane & 3;
  const int sc = (c4 ^ (r0 & 3)) << 3;     // pre-swizzled source k-offset (u16)

  auto STAGE = [&](u16* buf, int kt) {
#pragma unroll
    for (int i = 0; i < 2; ++i) {
      int ch = wid + i * 4;                 // chunk 0..7 = 16 rows each
      long rbase = (long)(ch * 16 + r0);
      gload_lds16(Ab + rbase * ld + kt + sc, buf + ch * 512);
      gload_lds16(Bb + rbase * ld + kt + sc, buf + 4096 + ch * 512);
    }
  };
  auto COMP = [&](const u16* buf) {
    const int ko = ((hi ^ (fr & 3)) << 3);  // swizzled slot for k-chunk hi
    s16x8 af[4], bf[4];
#pragma unroll
    for (int m = 0; m < 4; ++m) af[m] = ld8(buf + (wm * 64 + m * 16 + fr) * 32 + ko);
#pragma unroll
    for (int n = 0; n < 4; ++n) bf[n] = ld8(buf + 4096 + (wn * 64 + n * 16 + fr) * 32 + ko);
#pragma unroll
    for (int m = 0; m < 4; ++m)
#pragma unroll
      for (int n = 0; n < 4; ++n)
        acc[m][n] = __builtin_amdgcn_mfma_f32_16x16x32_bf16(af[m], bf[n], acc[m][n], 0, 0, 0);
  };

  const int nt = K >> 5;                    // 32 or 64: always even
  STAGE(lds, 0);
  __syncthreads();
  for (int t = 0; t < nt; t += 2) {
    STAGE(lds + 8192, (t + 1) << 5);        // prefetch t+1 while computing t
    COMP(lds);
    __syncthreads();                        // drains prefetch + readers of buf0
    if (t + 2 < nt) STAGE(lds, (t + 2) << 5);
    COMP(lds + 8192);
    __syncthreads();
  }
}

// ---------------- merged Q + KV projection GEMM (1536 blocks) ----------------
__global__ __launch_bounds__(256) void gemm_qkv(
    const u16* __restrict__ xnT, const u16* __restrict__ wq,
    const u16* __restrict__ ctxn, const u16* __restrict__ wkv,
    u16* __restrict__ qt, u16* __restrict__ kvt,
    const float* __restrict__ bq, const float* __restrict__ bkv) {
  __shared__ alignas(16) u16 lds[2 * 8192];
  const int tid = threadIdx.x, wid = tid >> 6, lane = tid & 63;
  const int orig = blockIdx.x;
  const int v = (orig & 7) * 192 + (orig >> 3);   // XCD chunk swizzle (1536/8)
  const u16 *Ab, *Bb; u16* C; const float* bias;
  int K, ld, ldc, bx, by;
  if (v < 1024) {           // Q: 16 batches x (8x8) tiles, batch-major
    int bz = v >> 6, r = v & 63; by = r >> 3; bx = r & 7;
    Ab = xnT + (long)bz * SS * CC + (long)bx * 128 * CC;
    Bb = wq + (long)by * 128 * CC;
    C  = qt + (long)bz * SS * CC;
    bias = bq; K = CC; ld = CC; ldc = CC;
  } else {                  // KV: 16 batches x (2x16) tiles
    int u = v - 1024;
    int bz = u >> 5, r = u & 31; by = r >> 1; bx = r & 1;
    Ab = ctxn + (long)bz * SKK * CTX + (long)bx * 128 * CTX;
    Bb = wkv + (long)by * 128 * CTX;
    C  = kvt + (long)bz * SKK * CTX;
    bias = bkv; K = CTX; ld = CTX; ldc = CTX;
  }
  f32x4 acc[4][4];
#pragma unroll
  for (int m = 0; m < 4; ++m)
#pragma unroll
    for (int n = 0; n < 4; ++n) acc[m][n] = zero4();

  gemm_core(Ab, Bb, K, ld, lds, acc, wid, lane);

  const int wm = wid >> 1, wn = wid & 1;
  const int fr = lane & 15, hi = lane >> 4;
  const int rowb = bx * 128 + wm * 64 + hi * 4;
  const int colb = by * 128 + wn * 64 + fr;
#pragma unroll
  for (int m = 0; m < 4; ++m) {
#pragma unroll
    for (int n = 0; n < 4; ++n) {
      int col = colb + n * 16;
      float bia = bias[col];
      float s = (col < CC) ? ATT_SCALE : 1.0f;   // q & k-half scaled
      f32x4 vv = acc[m][n];
#pragma unroll
      for (int i = 0; i < 4; ++i) {
        int row = rowb + m * 16 + i;
        C[(long)row * ldc + col] = f2bf((vv[i] + bia) * s);
      }
    }
  }
}

// ---------------- proj GEMM + bias + fp32 residual (1024 blocks) ----------------
__global__ __launch_bounds__(256) void gemm_proj(
    const u16* __restrict__ wp, const u16* __restrict__ at,
    float* __restrict__ out, const float* __restrict__ bp,
    const float* __restrict__ x) {
  __shared__ alignas(16) u16 lds[2 * 8192];
  const int tid = threadIdx.x, wid = tid >> 6, lane = tid & 63;
  const int orig = blockIdx.x;
  const int v = (orig & 7) * 128 + (orig >> 3);   // XCD chunk swizzle (1024/8)
  const int bz = v >> 6, r = v & 63, by = r >> 3, bx = r & 7;
  const u16* Ab = wp + (long)bx * 128 * CC;                   // rows = out-chan o
  const u16* Bb = at + (long)bz * SS * CC + (long)by * 128 * CC;  // rows = s
  f32x4 acc[4][4];
#pragma unroll
  for (int m = 0; m < 4; ++m)
#pragma unroll
    for (int n = 0; n < 4; ++n) acc[m][n] = zero4();

  gemm_core(Ab, Bb, CC, CC, lds, acc, wid, lane);

  float* C = out + (long)bz * SS * CC;
  const float* R = x + (long)bz * SS * CC;
  const int wm = wid >> 1, wn = wid & 1;
  const int fr = lane & 15, hi = lane >> 4;
  const int rowb = bx * 128 + wm * 64 + hi * 4;
  const int colb = by * 128 + wn * 64 + fr;
#pragma unroll
  for (int m = 0; m < 4; ++m) {
#pragma unroll
    for (int n = 0; n < 4; ++n) {
      int col = colb + n * 16;
      f32x4 vv = acc[m][n];
#pragma unroll
      for (int i = 0; i < 4; ++i) {
        int row = rowb + m * 16 + i;
        long idx = (long)row * CC + col;
        C[idx] = R[idx] + vv[i] + bp[row];
      }
    }
  }
}

// ---------------- transpose V half of kv_t -> v2[b][o(1024)][s'(256)]
__global__ __launch_bounds__(256) void transpose_v(const u16* __restrict__ kvt,
                                                   u16* __restrict__ v2) {
  __shared__ u16 t[64][66];
  const int b = blockIdx.z, s0 = blockIdx.y * 64, o0 = blockIdx.x * 64;
  const int tid = threadIdx.x, j = tid & 63, i0 = tid >> 6;
#pragma unroll
  for (int it = 0; it < 16; ++it) {
    int i = it * 4 + i0;
    t[i][j] = kvt[((long)b * SKK + s0 + i) * CTX + CC + o0 + j];
  }
  __syncthreads();
#pragma unroll
  for (int it = 0; it < 16; ++it) {
    int oi = it * 4 + i0;
    v2[((long)b * CC + o0 + oi) * SKK + s0 + j] = t[j][oi];
  }
}

// ---------------- fused attention (LDS-staged K/V, XCD chunk swizzle) -------------
__global__ __launch_bounds__(256) void attn_fused(const u16* __restrict__ qt,
                                                  const u16* __restrict__ kvt,
                                                  const u16* __restrict__ v2,
                                                  const float* __restrict__ mbias,
                                                  u16* __restrict__ at) {
  __shared__ alignas(16) u16 k_lds[256 * 64];   // 32KB K, later P (8KB/wave)
  __shared__ alignas(16) u16 v_lds[64 * 256];   // 32KB V
  const int orig = blockIdx.x + 16 * blockIdx.y + 256 * blockIdx.z;
  const int v = (orig & 7) * 512 + (orig >> 3);
  const int bb = v >> 8, h = (v >> 4) & 15, t0 = (v & 15) * 64;

  const int tid = threadIdx.x, wid = tid >> 6, lane = tid & 63;
  const int fr = lane & 15, hi = lane >> 4;
  const int sw = fr & 7;

#pragma unroll
  for (int it = 0; it < 8; ++it) {
    int lin = (wid * 8 + it) * 1024 + lane * 16;      // byte offset in LDS
    int kr = lin >> 7, kc = (lin >> 4) & 7;
    gload_lds16(kvt + ((long)bb * SKK + kr) * CTX + h * HD + ((kc ^ (kr & 7)) << 3),
                (const char*)k_lds + (wid * 8 + it) * 1024);
    int vr = lin >> 9, vc = (lin >> 4) & 31;
    gload_lds16(v2 + ((long)bb * CC + h * HD + vr) * SKK + ((vc ^ (vr & 7)) << 3),
                (const char*)v_lds + (wid * 8 + it) * 1024);
  }

  const u16* qp = qt + ((long)bb * SS + t0 + wid * 16 + fr) * CC + h * HD + hi * 8;
  s16x8 aq0 = ld8(qp), aq1 = ld8(qp + 32);

  __syncthreads();

  f32x4 sc[16];
#pragma unroll
  for (int nf = 0; nf < 16; ++nf) {
    const u16* krow = k_lds + (nf * 16 + fr) * 64;
    s16x8 kb0 = ld8(krow + (((hi) ^ sw) << 3));
    s16x8 kb1 = ld8(krow + (((4 + hi) ^ sw) << 3));
    f32x4 z = zero4();
    z = __builtin_amdgcn_mfma_f32_16x16x32_bf16(aq0, kb0, z, 0, 0, 0);
    sc[nf] = __builtin_amdgcn_mfma_f32_16x16x32_bf16(aq1, kb1, z, 0, 0, 0);
  }

  __syncthreads();   // all waves done reading K -> safe to overwrite with P

  const float* mb = mbias + bb * SKK + fr;
#pragma unroll
  for (int nf = 0; nf < 16; ++nf) sc[nf] = sc[nf] + mb[nf * 16];

#pragma unroll
  for (int i = 0; i < 4; ++i) {
    float m = sc[0][i];
#pragma unroll
    for (int nf = 1; nf < 16; ++nf) m = fmaxf(m, sc[nf][i]);
#pragma unroll
    for (int d = 1; d < 16; d <<= 1) m = fmaxf(m, __shfl_xor(m, d));
    float s = 0.f;
#pragma unroll
    for (int nf = 0; nf < 16; ++nf) {
      float e = __expf(sc[nf][i] - m);
      sc[nf][i] = e; s += e;
    }
#pragma unroll
    for (int d = 1; d < 16; d <<= 1) s += __shfl_xor(s, d);
    float inv = 1.0f / s;
#pragma unroll
    for (int nf = 0; nf < 16; ++nf) sc[nf][i] *= inv;
  }

  u16* p_base = k_lds + wid * 4096;
#pragma unroll
  for (int nf = 0; nf < 16; ++nf) {
    int c = 2 * nf + (fr >> 3);
#pragma unroll
    for (int i = 0; i < 4; ++i) {
      int t = 4 * hi + i;
      p_base[t * 256 + (((c ^ (t & 7)) << 3)) + sw] = f2bf(sc[nf][i]);
    }
  }

  f32x4 ov[4];
#pragma unroll
  for (int n = 0; n < 4; ++n) ov[n] = zero4();
#pragma unroll
  for (int kk = 0; kk < 8; ++kk) {
    int c = 4 * kk + hi;
    s16x8 pa = ld8(p_base + fr * 256 + ((c ^ sw) << 3));
#pragma unroll
    for (int n = 0; n < 4; ++n) {
      int o = n * 16 + fr;
      s16x8 vb = ld8(v_lds + o * 256 + ((c ^ sw) << 3));
      ov[n] = __builtin_amdgcn_mfma_f32_16x16x32_bf16(pa, vb, ov[n], 0, 0, 0);
    }
  }

  const int rbase = hi * 4;
  u16* po = at + ((long)bb * SS + t0 + wid * 16 + rbase) * CC + h * HD + fr;
#pragma unroll
  for (int n = 0; n < 4; ++n)
#pragma unroll
    for (int i = 0; i < 4; ++i) po[(long)i * CC + n * 16] = f2bf(ov[n][i]);
}

// ---------------- launcher ----------------
extern "C" void kernel_launch(void* const* d_in, const int* in_sizes, int n_in,
                              void* d_out, int out_size, void* d_ws, size_t ws_size,
                              hipStream_t stream) {
  const float* x       = (const float*)d_in[0];
  const float* context = (const float*)d_in[1];
  const int*   mask    = (const int*)d_in[2];
  const float* gamma_x = (const float*)d_in[3];
  const float* beta_x  = (const float*)d_in[4];
  const float* gamma_c = (const float*)d_in[5];
  const float* beta_c  = (const float*)d_in[6];
  const float* Wq      = (const float*)d_in[7];
  const float* bq      = (const float*)d_in[8];
  const float* Wkv     = (const float*)d_in[9];
  const float* bkv     = (const float*)d_in[10];
  const float* Wp      = (const float*)d_in[11];
  const float* bp      = (const float*)d_in[12];
  float* out = (float*)d_out;

  char* w = (char*)d_ws;
  size_t off = 0;
  u16* wq_bf  = (u16*)(w + off); off += (size_t)CC * CC * 2;
  u16* wkv_bf = (u16*)(w + off); off += (size_t)CTX * CTX * 2;
  u16* wp_bf  = (u16*)(w + off); off += (size_t)CC * CC * 2;
  u16* xnT    = (u16*)(w + off); off += (size_t)BB * SS * CC * 2;
  u16* ctxn   = (u16*)(w + off); off += (size_t)BB * SKK * CTX * 2;
  u16* qt     = (u16*)(w + off); off += (size_t)BB * SS * CC * 2;
  u16* kvt    = (u16*)(w + off); off += (size_t)BB * SKK * CTX * 2;
  u16* v2     = (u16*)(w + off); off += (size_t)BB * CC * SKK * 2;
  u16* at     = (u16*)(w + off); off += (size_t)BB * SS * CC * 2;
  float* mb   = (float*)(w + off); off += (size_t)BB * SKK * 4;
  float* stx  = (float*)(w + off); off += (size_t)BB * NG * 2 * 4;
  float* stc  = (float*)(w + off); off += (size_t)BB * NG * 2 * 4;
  (void)ws_size; (void)in_sizes; (void)n_in; (void)out_size;

  prep_misc<<<6160, 256, 0, stream>>>(Wq, Wkv, Wp, mask, wq_bf, wkv_bf, wp_bf, mb);

  gn_stats_all<<<1024, 256, 0, stream>>>(x, context, stx, stc);

  gn_apply_all<<<12288, 256, 0, stream>>>(x, context, stx, stc,
                                          gamma_x, beta_x, gamma_c, beta_c,
                                          xnT, ctxn);

  gemm_qkv<<<1536, 256, 0, stream>>>(xnT, wq_bf, ctxn, wkv_bf, qt, kvt, bq, bkv);

  transpose_v<<<dim3(16, 4, BB), 256, 0, stream>>>(kvt, v2);

  attn_fused<<<dim3(16, NH, BB), 256, 0, stream>>>(qt, kvt, v2, mb, at);

  gemm_proj<<<1024, 256, 0, stream>>>(wp_bf, at, out, bp, x);
}

// Round 8
// 413.631 us; speedup vs baseline: 1.0850x; 1.0850x over previous
//
#include <hip/hip_runtime.h>
#include <stdint.h>

#define DEV static __device__ __forceinline__

typedef unsigned short u16;
typedef u16  u16x8 __attribute__((ext_vector_type(8)));
typedef u16  u16x4 __attribute__((ext_vector_type(4)));
typedef float f32x4 __attribute__((ext_vector_type(4)));
typedef short s16x8 __attribute__((ext_vector_type(8)));   // 8 bf16 as shorts

// problem dims
#define BB 16
#define CC 1024
#define SS 1024      // Sq = 32*32
#define CTX 2048
#define SKK 256
#define NH 16
#define HD 64
#define NG 32
#define ATT_SCALE 0.35355339059327373f   // 1/64^0.25

DEV u16 f2bf(float f) {                    // fp32 -> bf16 RNE
  uint32_t u = __float_as_uint(f);
  return (u16)((u + 0x7fffu + ((u >> 16) & 1u)) >> 16);
}
DEV s16x8 ld8(const u16* p) { return __builtin_bit_cast(s16x8, *(const u16x8*)p); }
DEV f32x4 zero4() { f32x4 z = {0.f, 0.f, 0.f, 0.f}; return z; }

// async global->LDS, 16B per lane. LDS dst is wave-uniform base + lane*16.
DEV void gload_lds16(const void* g, const void* l) {
  __builtin_amdgcn_global_load_lds(
      (const __attribute__((address_space(1))) unsigned int*)(uintptr_t)g,
      (__attribute__((address_space(3))) unsigned int*)(uint32_t)(uintptr_t)l,
      16, 0, 0);
}

// ---------------- prep: weights fp32->bf16 (3 tensors) + mask bias ----------------
__global__ __launch_bounds__(256) void prep_misc(const float* __restrict__ Wq,
                                                 const float* __restrict__ Wkv,
                                                 const float* __restrict__ Wp,
                                                 const int* __restrict__ mask,
                                                 u16* __restrict__ wq_bf,
                                                 u16* __restrict__ wkv_bf,
                                                 u16* __restrict__ wp_bf,
                                                 float* __restrict__ mb) {
  const int bid = blockIdx.x, tid = threadIdx.x;
  const float* src; u16* dst; int i;
  if (bid < 1024)      { src = Wq;  dst = wq_bf;  i = bid * 256 + tid; }
  else if (bid < 5120) { src = Wkv; dst = wkv_bf; i = (bid - 1024) * 256 + tid; }
  else if (bid < 6144) { src = Wp;  dst = wp_bf;  i = (bid - 5120) * 256 + tid; }
  else {
    int j = (bid - 6144) * 256 + tid;
    mb[j] = mask[j] ? 0.f : -1e9f;
    return;
  }
  f32x4 v = ((const f32x4*)src)[i];
  u16x4 o; o[0]=f2bf(v[0]); o[1]=f2bf(v[1]); o[2]=f2bf(v[2]); o[3]=f2bf(v[3]);
  ((u16x4*)dst)[i] = o;
}

// ---------------- GroupNorm stats (x: blocks 0..511, ctx: 512..1023) ----
__global__ __launch_bounds__(256) void gn_stats_all(const float* __restrict__ x,
                                                    const float* __restrict__ ctx,
                                                    float* __restrict__ stx,
                                                    float* __restrict__ stc) {
  const int bid = blockIdx.x, tid = threadIdx.x;
  float s = 0.f, ss = 0.f;
  float* st; int slot; float inv_n;
  if (bid < 512) {
    const int b = bid >> 5, g = bid & 31;
    const float* p = x + ((size_t)b * CC + g * 32) * SS;
    for (int it = 0; it < 32; ++it) {
      f32x4 v = *(const f32x4*)(p + it * 1024 + tid * 4);
      s  += v[0] + v[1] + v[2] + v[3];
      ss += v[0]*v[0] + v[1]*v[1] + v[2]*v[2] + v[3]*v[3];
    }
    st = stx; slot = bid; inv_n = 1.f / 32768.f;
  } else {
    const int bid2 = bid - 512;
    const int b = bid2 >> 5, g = bid2 & 31;
    const float* p = ctx + (size_t)b * SKK * CTX + g * 64;
    const int ch = tid & 63, r0 = tid >> 6;
    for (int it = 0; it < 64; ++it) {
      float v = p[(size_t)(it * 4 + r0) * CTX + ch];
      s += v; ss += v * v;
    }
    st = stc; slot = bid2; inv_n = 1.f / 16384.f;
  }
  __shared__ float red[512];
  red[tid] = s; red[256 + tid] = ss;
  __syncthreads();
  for (int o = 128; o > 0; o >>= 1) {
    if (tid < o) { red[tid] += red[tid + o]; red[256 + tid] += red[256 + tid + o]; }
    __syncthreads();
  }
  if (tid == 0) {
    float mean = red[0] * inv_n;
    float var  = red[256] * inv_n - mean * mean;
    st[slot * 2 + 0] = mean;
    st[slot * 2 + 1] = rsqrtf(var + 1e-5f);
  }
}

// ---------------- GroupNorm apply (ctx: blocks 0..8191; x-transpose: 8192..) --
__global__ __launch_bounds__(256) void gn_apply_all(const float* __restrict__ x,
                                                    const float* __restrict__ ctx,
                                                    const float* __restrict__ stx,
                                                    const float* __restrict__ stc,
                                                    const float* __restrict__ gamma_x,
                                                    const float* __restrict__ beta_x,
                                                    const float* __restrict__ gamma_c,
                                                    const float* __restrict__ beta_c,
                                                    u16* __restrict__ xnT,
                                                    u16* __restrict__ ctxn) {
  __shared__ float t[64][65];
  const int bid = blockIdx.x, tid = threadIdx.x;
  if (bid < 8192) {
    size_t i = ((size_t)bid * 256 + tid) * 4;
    int ch = (int)(i & 2047);
    int bs = (int)(i >> 11);
    int b = bs >> 8;
    int g = ch >> 6;
    float mean = stc[(b * 32 + g) * 2], rstd = stc[(b * 32 + g) * 2 + 1];
    f32x4 v  = *(const f32x4*)(ctx + i);
    f32x4 ga = *(const f32x4*)(gamma_c + ch);
    f32x4 be = *(const f32x4*)(beta_c + ch);
    u16x4 o;
    o[0] = f2bf((v[0] - mean) * rstd * ga[0] + be[0]);
    o[1] = f2bf((v[1] - mean) * rstd * ga[1] + be[1]);
    o[2] = f2bf((v[2] - mean) * rstd * ga[2] + be[2]);
    o[3] = f2bf((v[3] - mean) * rstd * ga[3] + be[3]);
    *(u16x4*)(ctxn + i) = o;
    return;
  }
  const int id2 = bid - 8192;                       // [0, 4096)
  const int b = id2 >> 8, c0 = ((id2 >> 4) & 15) * 64, s0 = (id2 & 15) * 64;
  const int j = tid & 63, i0 = tid >> 6;
  for (int it = 0; it < 16; ++it) {
    int i = it * 4 + i0;
    int c = c0 + i;
    int g = c >> 5;
    float mean = stx[(b * 32 + g) * 2], rstd = stx[(b * 32 + g) * 2 + 1];
    float v = x[((size_t)b * CC + c) * SS + s0 + j];
    t[i][j] = (v - mean) * rstd * gamma_x[c] + beta_x[c];
  }
  __syncthreads();
  for (int it = 0; it < 16; ++it) {
    int jj = it * 4 + i0;
    xnT[((size_t)b * SS + s0 + jj) * CC + c0 + j] = f2bf(t[j][jj]);
  }
}

// ---------------- GEMM core: 128x128 tile, BK=32, 2-phase double-buffered,
// chunk-XOR-swizzled LDS via pre-swizzled global source (LDS dest linear).
DEV void gemm_core(const u16* __restrict__ Ab, const u16* __restrict__ Bb,
                   int K, int ld, u16* lds, f32x4 acc[4][4], int wid, int lane) {
  const int wm = wid >> 1, wn = wid & 1;
  const int fr = lane & 15, hi = lane >> 4;
  const int r0 = lane >> 2, c4 = lane & 3;
  const int sc = (c4 ^ (r0 & 3)) << 3;     // pre-swizzled source k-offset (u16)

  auto STAGE = [&](u16* buf, int kt) {
#pragma unroll
    for (int i = 0; i < 2; ++i) {
      int ch = wid + i * 4;                 // chunk 0..7 = 16 rows each
      long rbase = (long)(ch * 16 + r0);
      gload_lds16(Ab + rbase * ld + kt + sc, buf + ch * 512);
      gload_lds16(Bb + rbase * ld + kt + sc, buf + 4096 + ch * 512);
    }
  };
  auto COMP = [&](const u16* buf) {
    const int ko = ((hi ^ (fr & 3)) << 3);  // swizzled slot for k-chunk hi
    s16x8 af[4], bf[4];
#pragma unroll
    for (int m = 0; m < 4; ++m) af[m] = ld8(buf + (wm * 64 + m * 16 + fr) * 32 + ko);
#pragma unroll
    for (int n = 0; n < 4; ++n) bf[n] = ld8(buf + 4096 + (wn * 64 + n * 16 + fr) * 32 + ko);
#pragma unroll
    for (int m = 0; m < 4; ++m)
#pragma unroll
      for (int n = 0; n < 4; ++n)
        acc[m][n] = __builtin_amdgcn_mfma_f32_16x16x32_bf16(af[m], bf[n], acc[m][n], 0, 0, 0);
  };

  const int nt = K >> 5;                    // 32 or 64: always even
  STAGE(lds, 0);
  __syncthreads();
  for (int t = 0; t < nt; t += 2) {
    STAGE(lds + 8192, (t + 1) << 5);        // prefetch t+1 while computing t
    COMP(lds);
    __syncthreads();
    if (t + 2 < nt) STAGE(lds, (t + 2) << 5);
    COMP(lds + 8192);
    __syncthreads();
  }
}

// ---------------- merged Q + KV projection GEMM (1536 blocks, cycle-balanced) ----
// Per XCD (blockIdx%8): 128 Q-tiles (32 K-steps) + 64 KV-tiles (64 K-steps)
// = 4096+4096 steps -> even load. KV V-half tiles write v2 transposed directly.
__global__ __launch_bounds__(256) void gemm_qkv(
    const u16* __restrict__ xnT, const u16* __restrict__ wq,
    const u16* __restrict__ ctxn, const u16* __restrict__ wkv,
    u16* __restrict__ qt, u16* __restrict__ kvt, u16* __restrict__ v2,
    const float* __restrict__ bq, const float* __restrict__ bkv) {
  __shared__ alignas(16) u16 lds[2 * 8192];
  const int tid = threadIdx.x, wid = tid >> 6, lane = tid & 63;
  const int xcd = blockIdx.x & 7, l = blockIdx.x >> 3;
  const bool isQ = l < 128;
  const u16 *Ab, *Bb; const float* bias;
  int K, ld, bx, by, bz;
  if (isQ) {                 // Q: tiles xcd*128 + l, batch-major (2 batches/XCD)
    int q = xcd * 128 + l;
    bz = q >> 6; int r = q & 63; by = r >> 3; bx = r & 7;
    Ab = xnT + (long)bz * SS * CC + (long)bx * 128 * CC;
    Bb = wq + (long)by * 128 * CC;
    bias = bq; K = CC; ld = CC;
  } else {                   // KV: tiles xcd*64 + (l-128), batch-major
    int k = xcd * 64 + (l - 128);
    bz = k >> 5; int r = k & 31; by = r >> 1; bx = r & 1;
    Ab = ctxn + (long)bz * SKK * CTX + (long)bx * 128 * CTX;
    Bb = wkv + (long)by * 128 * CTX;
    bias = bkv; K = CTX; ld = CTX;
  }
  f32x4 acc[4][4];
#pragma unroll
  for (int m = 0; m < 4; ++m)
#pragma unroll
    for (int n = 0; n < 4; ++n) acc[m][n] = zero4();

  gemm_core(Ab, Bb, K, ld, lds, acc, wid, lane);

  const int wm = wid >> 1, wn = wid & 1;
  const int fr = lane & 15, hi = lane >> 4;
  const int rowb = bx * 128 + wm * 64 + hi * 4;
  const int colb = by * 128 + wn * 64 + fr;

  if (isQ) {
    u16* C = qt + (long)bz * SS * CC;
#pragma unroll
    for (int m = 0; m < 4; ++m)
#pragma unroll
      for (int n = 0; n < 4; ++n) {
        int col = colb + n * 16;
        float bia = bias[col];
        f32x4 vv = acc[m][n];
#pragma unroll
        for (int i = 0; i < 4; ++i)
          C[(long)(rowb + m * 16 + i) * CC + col] = f2bf((vv[i] + bia) * ATT_SCALE);
      }
  } else if (by < 8) {       // K half -> kvt rows (scaled)
    u16* C = kvt + (long)bz * SKK * CTX;
#pragma unroll
    for (int m = 0; m < 4; ++m)
#pragma unroll
      for (int n = 0; n < 4; ++n) {
        int col = colb + n * 16;
        float bia = bias[col];
        f32x4 vv = acc[m][n];
#pragma unroll
        for (int i = 0; i < 4; ++i)
          C[(long)(rowb + m * 16 + i) * CTX + col] = f2bf((vv[i] + bia) * ATT_SCALE);
      }
  } else {                   // V half -> v2[b][o][s'] transposed, packed 8B stores
    u16* V = v2 + (long)bz * CC * SKK;
#pragma unroll
    for (int m = 0; m < 4; ++m)
#pragma unroll
      for (int n = 0; n < 4; ++n) {
        int col = colb + n * 16;           // 1024..2047
        float bia = bias[col];
        f32x4 vv = acc[m][n];
        u16x4 pk;
#pragma unroll
        for (int i = 0; i < 4; ++i) pk[i] = f2bf(vv[i] + bia);
        *(u16x4*)(V + (long)(col - CC) * SKK + rowb + m * 16) = pk;
      }
  }
}

// ---------------- proj GEMM + bias + fp32 residual (1024 blocks) ----------------
__global__ __launch_bounds__(256) void gemm_proj(
    const u16* __restrict__ wp, const u16* __restrict__ at,
    float* __restrict__ out, const float* __restrict__ bp,
    const float* __restrict__ x) {
  __shared__ alignas(16) u16 lds[2 * 8192];
  const int tid = threadIdx.x, wid = tid >> 6, lane = tid & 63;
  const int orig = blockIdx.x;
  const int v = (orig & 7) * 128 + (orig >> 3);   // XCD chunk swizzle (1024/8)
  const int bz = v >> 6, r = v & 63, by = r >> 3, bx = r & 7;
  const u16* Ab = wp + (long)bx * 128 * CC;                   // rows = out-chan o
  const u16* Bb = at + (long)bz * SS * CC + (long)by * 128 * CC;  // rows = s
  f32x4 acc[4][4];
#pragma unroll
  for (int m = 0; m < 4; ++m)
#pragma unroll
    for (int n = 0; n < 4; ++n) acc[m][n] = zero4();

  gemm_core(Ab, Bb, CC, CC, lds, acc, wid, lane);

  float* C = out + (long)bz * SS * CC;
  const float* R = x + (long)bz * SS * CC;
  const int wm = wid >> 1, wn = wid & 1;
  const int fr = lane & 15, hi = lane >> 4;
  const int rowb = bx * 128 + wm * 64 + hi * 4;
  const int colb = by * 128 + wn * 64 + fr;
#pragma unroll
  for (int m = 0; m < 4; ++m) {
#pragma unroll
    for (int n = 0; n < 4; ++n) {
      int col = colb + n * 16;
      f32x4 vv = acc[m][n];
#pragma unroll
      for (int i = 0; i < 4; ++i) {
        int row = rowb + m * 16 + i;
        long idx = (long)row * CC + col;
        C[idx] = R[idx] + vv[i] + bp[row];
      }
    }
  }
}

// ---------------- fused attention (LDS-staged K/V, XCD chunk swizzle) -------------
__global__ __launch_bounds__(256) void attn_fused(const u16* __restrict__ qt,
                                                  const u16* __restrict__ kvt,
                                                  const u16* __restrict__ v2,
                                                  const float* __restrict__ mbias,
                                                  u16* __restrict__ at) {
  __shared__ alignas(16) u16 k_lds[256 * 64];   // 32KB K, later P (8KB/wave)
  __shared__ alignas(16) u16 v_lds[64 * 256];   // 32KB V
  const int orig = blockIdx.x + 16 * blockIdx.y + 256 * blockIdx.z;
  const int v = (orig & 7) * 512 + (orig >> 3);
  const int bb = v >> 8, h = (v >> 4) & 15, t0 = (v & 15) * 64;

  const int tid = threadIdx.x, wid = tid >> 6, lane = tid & 63;
  const int fr = lane & 15, hi = lane >> 4;
  const int sw = fr & 7;

#pragma unroll
  for (int it = 0; it < 8; ++it) {
    int lin = (wid * 8 + it) * 1024 + lane * 16;      // byte offset in LDS
    int kr = lin >> 7, kc = (lin >> 4) & 7;
    gload_lds16(kvt + ((long)bb * SKK + kr) * CTX + h * HD + ((kc ^ (kr & 7)) << 3),
                (const char*)k_lds + (wid * 8 + it) * 1024);
    int vr = lin >> 9, vc = (lin >> 4) & 31;
    gload_lds16(v2 + ((long)bb * CC + h * HD + vr) * SKK + ((vc ^ (vr & 7)) << 3),
                (const char*)v_lds + (wid * 8 + it) * 1024);
  }

  const u16* qp = qt + ((long)bb * SS + t0 + wid * 16 + fr) * CC + h * HD + hi * 8;
  s16x8 aq0 = ld8(qp), aq1 = ld8(qp + 32);

  __syncthreads();

  f32x4 sc[16];
#pragma unroll
  for (int nf = 0; nf < 16; ++nf) {
    const u16* krow = k_lds + (nf * 16 + fr) * 64;
    s16x8 kb0 = ld8(krow + (((hi) ^ sw) << 3));
    s16x8 kb1 = ld8(krow + (((4 + hi) ^ sw) << 3));
    f32x4 z = zero4();
    z = __builtin_amdgcn_mfma_f32_16x16x32_bf16(aq0, kb0, z, 0, 0, 0);
    sc[nf] = __builtin_amdgcn_mfma_f32_16x16x32_bf16(aq1, kb1, z, 0, 0, 0);
  }

  __syncthreads();   // all waves done reading K -> safe to overwrite with P

  const float* mb = mbias + bb * SKK + fr;
#pragma unroll
  for (int nf = 0; nf < 16; ++nf) sc[nf] = sc[nf] + mb[nf * 16];

#pragma unroll
  for (int i = 0; i < 4; ++i) {
    float m = sc[0][i];
#pragma unroll
    for (int nf = 1; nf < 16; ++nf) m = fmaxf(m, sc[nf][i]);
#pragma unroll
    for (int d = 1; d < 16; d <<= 1) m = fmaxf(m, __shfl_xor(m, d));
    float s = 0.f;
#pragma unroll
    for (int nf = 0; nf < 16; ++nf) {
      float e = __expf(sc[nf][i] - m);
      sc[nf][i] = e; s += e;
    }
#pragma unroll
    for (int d = 1; d < 16; d <<= 1) s += __shfl_xor(s, d);
    float inv = 1.0f / s;
#pragma unroll
    for (int nf = 0; nf < 16; ++nf) sc[nf][i] *= inv;
  }

  u16* p_base = k_lds + wid * 4096;
#pragma unroll
  for (int nf = 0; nf < 16; ++nf) {
    int c = 2 * nf + (fr >> 3);
#pragma unroll
    for (int i = 0; i < 4; ++i) {
      int t = 4 * hi + i;
      p_base[t * 256 + (((c ^ (t & 7)) << 3)) + sw] = f2bf(sc[nf][i]);
    }
  }

  f32x4 ov[4];
#pragma unroll
  for (int n = 0; n < 4; ++n) ov[n] = zero4();
#pragma unroll
  for (int kk = 0; kk < 8; ++kk) {
    int c = 4 * kk + hi;
    s16x8 pa = ld8(p_base + fr * 256 + ((c ^ sw) << 3));
#pragma unroll
    for (int n = 0; n < 4; ++n) {
      int o = n * 16 + fr;
      s16x8 vb = ld8(v_lds + o * 256 + ((c ^ sw) << 3));
      ov[n] = __builtin_amdgcn_mfma_f32_16x16x32_bf16(pa, vb, ov[n], 0, 0, 0);
    }
  }

  const int rbase = hi * 4;
  u16* po = at + ((long)bb * SS + t0 + wid * 16 + rbase) * CC + h * HD + fr;
#pragma unroll
  for (int n = 0; n < 4; ++n)
#pragma unroll
    for (int i = 0; i < 4; ++i) po[(long)i * CC + n * 16] = f2bf(ov[n][i]);
}

// ---------------- launcher ----------------
extern "C" void kernel_launch(void* const* d_in, const int* in_sizes, int n_in,
                              void* d_out, int out_size, void* d_ws, size_t ws_size,
                              hipStream_t stream) {
  const float* x       = (const float*)d_in[0];
  const float* context = (const float*)d_in[1];
  const int*   mask    = (const int*)d_in[2];
  const float* gamma_x = (const float*)d_in[3];
  const float* beta_x  = (const float*)d_in[4];
  const float* gamma_c = (const float*)d_in[5];
  const float* beta_c  = (const float*)d_in[6];
  const float* Wq      = (const float*)d_in[7];
  const float* bq      = (const float*)d_in[8];
  const float* Wkv     = (const float*)d_in[9];
  const float* bkv     = (const float*)d_in[10];
  const float* Wp      = (const float*)d_in[11];
  const float* bp      = (const float*)d_in[12];
  float* out = (float*)d_out;

  char* w = (char*)d_ws;
  size_t off = 0;
  u16* wq_bf  = (u16*)(w + off); off += (size_t)CC * CC * 2;
  u16* wkv_bf = (u16*)(w + off); off += (size_t)CTX * CTX * 2;
  u16* wp_bf  = (u16*)(w + off); off += (size_t)CC * CC * 2;
  u16* xnT    = (u16*)(w + off); off += (size_t)BB * SS * CC * 2;
  u16* ctxn   = (u16*)(w + off); off += (size_t)BB * SKK * CTX * 2;
  u16* qt     = (u16*)(w + off); off += (size_t)BB * SS * CC * 2;
  u16* kvt    = (u16*)(w + off); off += (size_t)BB * SKK * CTX * 2;
  u16* v2     = (u16*)(w + off); off += (size_t)BB * CC * SKK * 2;
  u16* at     = (u16*)(w + off); off += (size_t)BB * SS * CC * 2;
  float* mb   = (float*)(w + off); off += (size_t)BB * SKK * 4;
  float* stx  = (float*)(w + off); off += (size_t)BB * NG * 2 * 4;
  float* stc  = (float*)(w + off); off += (size_t)BB * NG * 2 * 4;
  (void)ws_size; (void)in_sizes; (void)n_in; (void)out_size;

  prep_misc<<<6160, 256, 0, stream>>>(Wq, Wkv, Wp, mask, wq_bf, wkv_bf, wp_bf, mb);

  gn_stats_all<<<1024, 256, 0, stream>>>(x, context, stx, stc);

  gn_apply_all<<<12288, 256, 0, stream>>>(x, context, stx, stc,
                                          gamma_x, beta_x, gamma_c, beta_c,
                                          xnT, ctxn);

  gemm_qkv<<<1536, 256, 0, stream>>>(xnT, wq_bf, ctxn, wkv_bf, qt, kvt, v2, bq, bkv);

  attn_fused<<<dim3(16, NH, BB), 256, 0, stream>>>(qt, kvt, v2, mb, at);

  gemm_proj<<<1024, 256, 0, stream>>>(wp_bf, at, out, bp, x);
}

// Round 9
// 389.877 us; speedup vs baseline: 1.1511x; 1.0609x over previous
//
#include <hip/hip_runtime.h>
#include <stdint.h>

#define DEV static __device__ __forceinline__

typedef unsigned short u16;
typedef u16  u16x8 __attribute__((ext_vector_type(8)));
typedef u16  u16x4 __attribute__((ext_vector_type(4)));
typedef float f32x4 __attribute__((ext_vector_type(4)));
typedef short s16x8 __attribute__((ext_vector_type(8)));   // 8 bf16 as shorts

// problem dims
#define BB 16
#define CC 1024
#define SS 1024      // Sq = 32*32
#define CTX 2048
#define SKK 256
#define NH 16
#define HD 64
#define NG 32
#define ATT_SCALE 0.35355339059327373f   // 1/64^0.25

DEV u16 f2bf(float f) {                    // fp32 -> bf16 RNE
  uint32_t u = __float_as_uint(f);
  return (u16)((u + 0x7fffu + ((u >> 16) & 1u)) >> 16);
}
DEV s16x8 ld8(const u16* p) { return __builtin_bit_cast(s16x8, *(const u16x8*)p); }
DEV f32x4 zero4() { f32x4 z = {0.f, 0.f, 0.f, 0.f}; return z; }

// async global->LDS, 16B per lane. LDS dst is wave-uniform base + lane*16.
DEV void gload_lds16(const void* g, const void* l) {
  __builtin_amdgcn_global_load_lds(
      (const __attribute__((address_space(1))) unsigned int*)(uintptr_t)g,
      (__attribute__((address_space(3))) unsigned int*)(uint32_t)(uintptr_t)l,
      16, 0, 0);
}

// ---------------- prep: weights fp32->bf16 (3 tensors) + mask bias ----------------
__global__ __launch_bounds__(256) void prep_misc(const float* __restrict__ Wq,
                                                 const float* __restrict__ Wkv,
                                                 const float* __restrict__ Wp,
                                                 const int* __restrict__ mask,
                                                 u16* __restrict__ wq_bf,
                                                 u16* __restrict__ wkv_bf,
                                                 u16* __restrict__ wp_bf,
                                                 float* __restrict__ mb) {
  const int bid = blockIdx.x, tid = threadIdx.x;
  const float* src; u16* dst; int i;
  if (bid < 1024)      { src = Wq;  dst = wq_bf;  i = bid * 256 + tid; }
  else if (bid < 5120) { src = Wkv; dst = wkv_bf; i = (bid - 1024) * 256 + tid; }
  else if (bid < 6144) { src = Wp;  dst = wp_bf;  i = (bid - 5120) * 256 + tid; }
  else {
    int j = (bid - 6144) * 256 + tid;
    mb[j] = mask[j] ? 0.f : -1e9f;
    return;
  }
  f32x4 v = ((const f32x4*)src)[i];
  u16x4 o; o[0]=f2bf(v[0]); o[1]=f2bf(v[1]); o[2]=f2bf(v[2]); o[3]=f2bf(v[3]);
  ((u16x4*)dst)[i] = o;
}

// ---------------- GroupNorm stats (x: blocks 0..511, ctx: 512..1023) ----
__global__ __launch_bounds__(256) void gn_stats_all(const float* __restrict__ x,
                                                    const float* __restrict__ ctx,
                                                    float* __restrict__ stx,
                                                    float* __restrict__ stc) {
  const int bid = blockIdx.x, tid = threadIdx.x;
  float s = 0.f, ss = 0.f;
  float* st; int slot; float inv_n;
  if (bid < 512) {
    const int b = bid >> 5, g = bid & 31;
    const float* p = x + ((size_t)b * CC + g * 32) * SS;
    for (int it = 0; it < 32; ++it) {
      f32x4 v = *(const f32x4*)(p + it * 1024 + tid * 4);
      s  += v[0] + v[1] + v[2] + v[3];
      ss += v[0]*v[0] + v[1]*v[1] + v[2]*v[2] + v[3]*v[3];
    }
    st = stx; slot = bid; inv_n = 1.f / 32768.f;
  } else {
    const int bid2 = bid - 512;
    const int b = bid2 >> 5, g = bid2 & 31;
    const float* p = ctx + (size_t)b * SKK * CTX + g * 64;
    const int ch = tid & 63, r0 = tid >> 6;
    for (int it = 0; it < 64; ++it) {
      float v = p[(size_t)(it * 4 + r0) * CTX + ch];
      s += v; ss += v * v;
    }
    st = stc; slot = bid2; inv_n = 1.f / 16384.f;
  }
  __shared__ float red[512];
  red[tid] = s; red[256 + tid] = ss;
  __syncthreads();
  for (int o = 128; o > 0; o >>= 1) {
    if (tid < o) { red[tid] += red[tid + o]; red[256 + tid] += red[256 + tid + o]; }
    __syncthreads();
  }
  if (tid == 0) {
    float mean = red[0] * inv_n;
    float var  = red[256] * inv_n - mean * mean;
    st[slot * 2 + 0] = mean;
    st[slot * 2 + 1] = rsqrtf(var + 1e-5f);
  }
}

// ---------------- GroupNorm apply (ctx: blocks 0..8191; x-transpose: 8192..) --
__global__ __launch_bounds__(256) void gn_apply_all(const float* __restrict__ x,
                                                    const float* __restrict__ ctx,
                                                    const float* __restrict__ stx,
                                                    const float* __restrict__ stc,
                                                    const float* __restrict__ gamma_x,
                                                    const float* __restrict__ beta_x,
                                                    const float* __restrict__ gamma_c,
                                                    const float* __restrict__ beta_c,
                                                    u16* __restrict__ xnT,
                                                    u16* __restrict__ ctxn) {
  __shared__ float t[64][65];
  const int bid = blockIdx.x, tid = threadIdx.x;
  if (bid < 8192) {
    size_t i = ((size_t)bid * 256 + tid) * 4;
    int ch = (int)(i & 2047);
    int bs = (int)(i >> 11);
    int b = bs >> 8;
    int g = ch >> 6;
    float mean = stc[(b * 32 + g) * 2], rstd = stc[(b * 32 + g) * 2 + 1];
    f32x4 v  = *(const f32x4*)(ctx + i);
    f32x4 ga = *(const f32x4*)(gamma_c + ch);
    f32x4 be = *(const f32x4*)(beta_c + ch);
    u16x4 o;
    o[0] = f2bf((v[0] - mean) * rstd * ga[0] + be[0]);
    o[1] = f2bf((v[1] - mean) * rstd * ga[1] + be[1]);
    o[2] = f2bf((v[2] - mean) * rstd * ga[2] + be[2]);
    o[3] = f2bf((v[3] - mean) * rstd * ga[3] + be[3]);
    *(u16x4*)(ctxn + i) = o;
    return;
  }
  const int id2 = bid - 8192;                       // [0, 4096)
  const int b = id2 >> 8, c0 = ((id2 >> 4) & 15) * 64, s0 = (id2 & 15) * 64;
  const int j = tid & 63, i0 = tid >> 6;
  for (int it = 0; it < 16; ++it) {
    int i = it * 4 + i0;
    int c = c0 + i;
    int g = c >> 5;
    float mean = stx[(b * 32 + g) * 2], rstd = stx[(b * 32 + g) * 2 + 1];
    float v = x[((size_t)b * CC + c) * SS + s0 + j];
    t[i][j] = (v - mean) * rstd * gamma_x[c] + beta_x[c];
  }
  __syncthreads();
  for (int it = 0; it < 16; ++it) {
    int jj = it * 4 + i0;
    xnT[((size_t)b * SS + s0 + jj) * CC + c0 + j] = f2bf(t[j][jj]);
  }
}

// ---------------- 8-phase-style GEMM core: 256x256 tile, 8 waves (2Mx4N),
// BK=64 as 2 units of K=32; 4-slot LDS FIFO (unit = A[256][32]+B[256][32]);
// counted vmcnt(8) + raw s_barrier: 3 units (12 loads/thread) always in flight.
// Per phase: 12 ds_read_b128 + stage(unit g+3) + 32 MFMA (setprio-wrapped).
// Tail stays uniform by re-staging the last unit into dead slots (race-free:
// slot reuse distance >= 3 phases; WAR ordered by the phase barrier).
DEV void gemm8_core(const u16* __restrict__ A, const u16* __restrict__ B,
                    int ld, int nu, u16* lds, f32x4 acc[8][4], int tid) {
  const int wid = tid >> 6, lane = tid & 63;
  const int wr = wid >> 2, wc = wid & 3;
  const int fr = lane & 15, hi = lane >> 4;
  const int rj0 = tid >> 2, kk = (tid & 3) * 8;

  auto STAGE = [&](int u) {
    int uc = u < nu ? u : nu - 1;
    int kof = (uc >> 1) * 64 + (uc & 1) * 32 + kk;
    u16* la = lds + (u & 3) * 16384;          // A slot; B at +8192
    gload_lds16(A + (long)rj0 * ld + kof,         la + tid * 8);
    gload_lds16(A + (long)(rj0 + 128) * ld + kof, la + 4096 + tid * 8);
    gload_lds16(B + (long)rj0 * ld + kof,         la + 8192 + tid * 8);
    gload_lds16(B + (long)(rj0 + 128) * ld + kof, la + 12288 + tid * 8);
  };

  STAGE(0); STAGE(1); STAGE(2);               // 12 insts/thread in flight

#pragma unroll 1
  for (int g = 0; g < nu; ++g) {
    asm volatile("s_waitcnt vmcnt(8)" ::: "memory");  // unit g landed; g+1,g+2 fly
    __builtin_amdgcn_s_barrier();
    __builtin_amdgcn_sched_barrier(0);
    const u16* As = lds + (g & 3) * 16384;
    const u16* Bs = As + 8192;
    s16x8 a[8], b[4];
#pragma unroll
    for (int m = 0; m < 8; ++m) a[m] = ld8(As + (wr * 128 + m * 16 + fr) * 32 + hi * 8);
#pragma unroll
    for (int n = 0; n < 4; ++n) b[n] = ld8(Bs + (wc * 64 + n * 16 + fr) * 32 + hi * 8);
    STAGE(g + 3);
    __builtin_amdgcn_s_setprio(1);
#pragma unroll
    for (int m = 0; m < 8; ++m)
#pragma unroll
      for (int n = 0; n < 4; ++n)
        acc[m][n] = __builtin_amdgcn_mfma_f32_16x16x32_bf16(a[m], b[n], acc[m][n], 0, 0, 0);
    __builtin_amdgcn_s_setprio(0);
  }
}

// ---------------- merged Q + KV projection GEMM (384 blocks x 512 thr) ----------
// Per XCD 48 blocks: l 0..15 = KV (64 units, dispatched first), l 16..47 = Q (32).
// Self-balances: ~half the CUs run one KV block, ~half run two Q blocks.
__global__ __launch_bounds__(512) void gemm_qkv8(
    const u16* __restrict__ xnT, const u16* __restrict__ wq,
    const u16* __restrict__ ctxn, const u16* __restrict__ wkv,
    u16* __restrict__ qt, u16* __restrict__ kvt, u16* __restrict__ v2,
    const float* __restrict__ bq, const float* __restrict__ bkv) {
  __shared__ alignas(16) u16 lds[65536];      // 128 KB: 4 slots x (A 8K + B 8K) u16
  const int tid = threadIdx.x;
  const int xcd = blockIdx.x & 7, l = blockIdx.x >> 3;
  const int wid = tid >> 6, lane = tid & 63;
  const int wr = wid >> 2, wc = wid & 3;
  const int fr = lane & 15, hi = lane >> 4;

  f32x4 acc[8][4];
#pragma unroll
  for (int m = 0; m < 8; ++m)
#pragma unroll
    for (int n = 0; n < 4; ++n) acc[m][n] = zero4();

  if (l < 16) {            // ---- KV: M=256 (s'), N tile tn of 8, K=2048 ----
    const int kvid = xcd * 16 + l;
    const int bz = kvid >> 3, tn = kvid & 7;
    const u16* A = ctxn + (long)bz * SKK * CTX;
    const u16* B = wkv + (long)tn * 256 * CTX;
    gemm8_core(A, B, CTX, 64, lds, acc, tid);

    const int rowb = wr * 128 + hi * 4;                 // s' base
    const int colb = tn * 256 + wc * 64 + fr;           // o2 base
    if (tn < 4) {          // K half -> kvt (scaled)
      u16* C = kvt + (long)bz * SKK * CTX;
#pragma unroll
      for (int m = 0; m < 8; ++m)
#pragma unroll
        for (int n = 0; n < 4; ++n) {
          int col = colb + n * 16;
          float bia = bkv[col];
          f32x4 vv = acc[m][n];
#pragma unroll
          for (int i = 0; i < 4; ++i)
            C[(long)(rowb + m * 16 + i) * CTX + col] = f2bf((vv[i] + bia) * ATT_SCALE);
        }
    } else {               // V half -> v2[b][o][s'] transposed, packed 8B stores
      u16* V = v2 + (long)bz * CC * SKK;
#pragma unroll
      for (int m = 0; m < 8; ++m)
#pragma unroll
        for (int n = 0; n < 4; ++n) {
          int col = colb + n * 16;                      // 1024..2047
          float bia = bkv[col];
          f32x4 vv = acc[m][n];
          u16x4 pk;
#pragma unroll
          for (int i = 0; i < 4; ++i) pk[i] = f2bf(vv[i] + bia);
          *(u16x4*)(V + (long)(col - CC) * SKK + rowb + m * 16) = pk;
        }
    }
  } else {                 // ---- Q: 256x256 tiles, K=1024 ----
    const int q = xcd * 32 + (l - 16);
    const int bz = q >> 4, tm = (q >> 2) & 3, tn = q & 3;
    const u16* A = xnT + (long)bz * SS * CC + (long)tm * 256 * CC;
    const u16* B = wq + (long)tn * 256 * CC;
    gemm8_core(A, B, CC, 32, lds, acc, tid);

    u16* C = qt + (long)bz * SS * CC;
    const int rowb = tm * 256 + wr * 128 + hi * 4;
    const int colb = tn * 256 + wc * 64 + fr;
#pragma unroll
    for (int m = 0; m < 8; ++m)
#pragma unroll
      for (int n = 0; n < 4; ++n) {
        int col = colb + n * 16;
        float bia = bq[col];
        f32x4 vv = acc[m][n];
#pragma unroll
        for (int i = 0; i < 4; ++i)
          C[(long)(rowb + m * 16 + i) * CC + col] = f2bf((vv[i] + bia) * ATT_SCALE);
      }
  }
}

// ---------------- proj GEMM + bias + fp32 residual (256 blocks x 512 thr) --------
__global__ __launch_bounds__(512) void gemm_proj8(
    const u16* __restrict__ wp, const u16* __restrict__ at,
    float* __restrict__ out, const float* __restrict__ bp,
    const float* __restrict__ x) {
  __shared__ alignas(16) u16 lds[65536];
  const int tid = threadIdx.x;
  const int v = (blockIdx.x & 7) * 32 + (blockIdx.x >> 3);
  const int bz = v >> 4, tm = (v >> 2) & 3, tn = v & 3;
  const int wid = tid >> 6, lane = tid & 63;
  const int wr = wid >> 2, wc = wid & 3;
  const int fr = lane & 15, hi = lane >> 4;

  f32x4 acc[8][4];
#pragma unroll
  for (int m = 0; m < 8; ++m)
#pragma unroll
    for (int n = 0; n < 4; ++n) acc[m][n] = zero4();

  const u16* A = wp + (long)tm * 256 * CC;                       // rows = o
  const u16* B = at + (long)bz * SS * CC + (long)tn * 256 * CC;  // rows = s
  gemm8_core(A, B, CC, 32, lds, acc, tid);

  float* C = out + (long)bz * CC * SS;
  const float* R = x + (long)bz * CC * SS;
  const int rowb = tm * 256 + wr * 128 + hi * 4;   // o
  const int colb = tn * 256 + wc * 64 + fr;        // s
#pragma unroll
  for (int m = 0; m < 8; ++m)
#pragma unroll
    for (int n = 0; n < 4; ++n) {
      int col = colb + n * 16;
      f32x4 vv = acc[m][n];
#pragma unroll
      for (int i = 0; i < 4; ++i) {
        int row = rowb + m * 16 + i;
        long idx = (long)row * SS + col;
        C[idx] = R[idx] + vv[i] + bp[row];
      }
    }
}

// ---------------- fused attention (LDS-staged K/V, XCD chunk swizzle) -------------
__global__ __launch_bounds__(256) void attn_fused(const u16* __restrict__ qt,
                                                  const u16* __restrict__ kvt,
                                                  const u16* __restrict__ v2,
                                                  const float* __restrict__ mbias,
                                                  u16* __restrict__ at) {
  __shared__ alignas(16) u16 k_lds[256 * 64];   // 32KB K, later P (8KB/wave)
  __shared__ alignas(16) u16 v_lds[64 * 256];   // 32KB V
  const int orig = blockIdx.x + 16 * blockIdx.y + 256 * blockIdx.z;
  const int v = (orig & 7) * 512 + (orig >> 3);
  const int bb = v >> 8, h = (v >> 4) & 15, t0 = (v & 15) * 64;

  const int tid = threadIdx.x, wid = tid >> 6, lane = tid & 63;
  const int fr = lane & 15, hi = lane >> 4;
  const int sw = fr & 7;

#pragma unroll
  for (int it = 0; it < 8; ++it) {
    int lin = (wid * 8 + it) * 1024 + lane * 16;      // byte offset in LDS
    int kr = lin >> 7, kc = (lin >> 4) & 7;
    gload_lds16(kvt + ((long)bb * SKK + kr) * CTX + h * HD + ((kc ^ (kr & 7)) << 3),
                (const char*)k_lds + (wid * 8 + it) * 1024);
    int vr = lin >> 9, vc = (lin >> 4) & 31;
    gload_lds16(v2 + ((long)bb * CC + h * HD + vr) * SKK + ((vc ^ (vr & 7)) << 3),
                (const char*)v_lds + (wid * 8 + it) * 1024);
  }

  const u16* qp = qt + ((long)bb * SS + t0 + wid * 16 + fr) * CC + h * HD + hi * 8;
  s16x8 aq0 = ld8(qp), aq1 = ld8(qp + 32);

  __syncthreads();

  f32x4 sc[16];
#pragma unroll
  for (int nf = 0; nf < 16; ++nf) {
    const u16* krow = k_lds + (nf * 16 + fr) * 64;
    s16x8 kb0 = ld8(krow + (((hi) ^ sw) << 3));
    s16x8 kb1 = ld8(krow + (((4 + hi) ^ sw) << 3));
    f32x4 z = zero4();
    z = __builtin_amdgcn_mfma_f32_16x16x32_bf16(aq0, kb0, z, 0, 0, 0);
    sc[nf] = __builtin_amdgcn_mfma_f32_16x16x32_bf16(aq1, kb1, z, 0, 0, 0);
  }

  __syncthreads();   // all waves done reading K -> safe to overwrite with P

  const float* mb = mbias + bb * SKK + fr;
#pragma unroll
  for (int nf = 0; nf < 16; ++nf) sc[nf] = sc[nf] + mb[nf * 16];

#pragma unroll
  for (int i = 0; i < 4; ++i) {
    float m = sc[0][i];
#pragma unroll
    for (int nf = 1; nf < 16; ++nf) m = fmaxf(m, sc[nf][i]);
#pragma unroll
    for (int d = 1; d < 16; d <<= 1) m = fmaxf(m, __shfl_xor(m, d));
    float s = 0.f;
#pragma unroll
    for (int nf = 0; nf < 16; ++nf) {
      float e = __expf(sc[nf][i] - m);
      sc[nf][i] = e; s += e;
    }
#pragma unroll
    for (int d = 1; d < 16; d <<= 1) s += __shfl_xor(s, d);
    float inv = 1.0f / s;
#pragma unroll
    for (int nf = 0; nf < 16; ++nf) sc[nf][i] *= inv;
  }

  u16* p_base = k_lds + wid * 4096;
#pragma unroll
  for (int nf = 0; nf < 16; ++nf) {
    int c = 2 * nf + (fr >> 3);
#pragma unroll
    for (int i = 0; i < 4; ++i) {
      int t = 4 * hi + i;
      p_base[t * 256 + (((c ^ (t & 7)) << 3)) + sw] = f2bf(sc[nf][i]);
    }
  }

  f32x4 ov[4];
#pragma unroll
  for (int n = 0; n < 4; ++n) ov[n] = zero4();
#pragma unroll
  for (int kk = 0; kk < 8; ++kk) {
    int c = 4 * kk + hi;
    s16x8 pa = ld8(p_base + fr * 256 + ((c ^ sw) << 3));
#pragma unroll
    for (int n = 0; n < 4; ++n) {
      int o = n * 16 + fr;
      s16x8 vb = ld8(v_lds + o * 256 + ((c ^ sw) << 3));
      ov[n] = __builtin_amdgcn_mfma_f32_16x16x32_bf16(pa, vb, ov[n], 0, 0, 0);
    }
  }

  const int rbase = hi * 4;
  u16* po = at + ((long)bb * SS + t0 + wid * 16 + rbase) * CC + h * HD + fr;
#pragma unroll
  for (int n = 0; n < 4; ++n)
#pragma unroll
    for (int i = 0; i < 4; ++i) po[(long)i * CC + n * 16] = f2bf(ov[n][i]);
}

// ---------------- launcher ----------------
extern "C" void kernel_launch(void* const* d_in, const int* in_sizes, int n_in,
                              void* d_out, int out_size, void* d_ws, size_t ws_size,
                              hipStream_t stream) {
  const float* x       = (const float*)d_in[0];
  const float* context = (const float*)d_in[1];
  const int*   mask    = (const int*)d_in[2];
  const float* gamma_x = (const float*)d_in[3];
  const float* beta_x  = (const float*)d_in[4];
  const float* gamma_c = (const float*)d_in[5];
  const float* beta_c  = (const float*)d_in[6];
  const float* Wq      = (const float*)d_in[7];
  const float* bq      = (const float*)d_in[8];
  const float* Wkv     = (const float*)d_in[9];
  const float* bkv     = (const float*)d_in[10];
  const float* Wp      = (const float*)d_in[11];
  const float* bp      = (const float*)d_in[12];
  float* out = (float*)d_out;

  char* w = (char*)d_ws;
  size_t off = 0;
  u16* wq_bf  = (u16*)(w + off); off += (size_t)CC * CC * 2;
  u16* wkv_bf = (u16*)(w + off); off += (size_t)CTX * CTX * 2;
  u16* wp_bf  = (u16*)(w + off); off += (size_t)CC * CC * 2;
  u16* xnT    = (u16*)(w + off); off += (size_t)BB * SS * CC * 2;
  u16* ctxn   = (u16*)(w + off); off += (size_t)BB * SKK * CTX * 2;
  u16* qt     = (u16*)(w + off); off += (size_t)BB * SS * CC * 2;
  u16* kvt    = (u16*)(w + off); off += (size_t)BB * SKK * CTX * 2;
  u16* v2     = (u16*)(w + off); off += (size_t)BB * CC * SKK * 2;
  u16* at     = (u16*)(w + off); off += (size_t)BB * SS * CC * 2;
  float* mb   = (float*)(w + off); off += (size_t)BB * SKK * 4;
  float* stx  = (float*)(w + off); off += (size_t)BB * NG * 2 * 4;
  float* stc  = (float*)(w + off); off += (size_t)BB * NG * 2 * 4;
  (void)ws_size; (void)in_sizes; (void)n_in; (void)out_size;

  prep_misc<<<6160, 256, 0, stream>>>(Wq, Wkv, Wp, mask, wq_bf, wkv_bf, wp_bf, mb);

  gn_stats_all<<<1024, 256, 0, stream>>>(x, context, stx, stc);

  gn_apply_all<<<12288, 256, 0, stream>>>(x, context, stx, stc,
                                          gamma_x, beta_x, gamma_c, beta_c,
                                          xnT, ctxn);

  gemm_qkv8<<<384, 512, 0, stream>>>(xnT, wq_bf, ctxn, wkv_bf, qt, kvt, v2, bq, bkv);

  attn_fused<<<dim3(16, NH, BB), 256, 0, stream>>>(qt, kvt, v2, mb, at);

  gemm_proj8<<<256, 512, 0, stream>>>(wp_bf, at, out, bp, x);
}

// Round 10
// 386.403 us; speedup vs baseline: 1.1615x; 1.0090x over previous
//
#include <hip/hip_runtime.h>
#include <stdint.h>

#define DEV static __device__ __forceinline__

typedef unsigned short u16;
typedef u16  u16x8 __attribute__((ext_vector_type(8)));
typedef u16  u16x4 __attribute__((ext_vector_type(4)));
typedef float f32x4 __attribute__((ext_vector_type(4)));
typedef short s16x8 __attribute__((ext_vector_type(8)));   // 8 bf16 as shorts

// problem dims
#define BB 16
#define CC 1024
#define SS 1024      // Sq = 32*32
#define CTX 2048
#define SKK 256
#define NH 16
#define HD 64
#define NG 32
#define ATT_SCALE 0.35355339059327373f   // 1/64^0.25

DEV u16 f2bf(float f) {                    // fp32 -> bf16 RNE
  uint32_t u = __float_as_uint(f);
  return (u16)((u + 0x7fffu + ((u >> 16) & 1u)) >> 16);
}
DEV s16x8 ld8(const u16* p) { return __builtin_bit_cast(s16x8, *(const u16x8*)p); }
DEV f32x4 zero4() { f32x4 z = {0.f, 0.f, 0.f, 0.f}; return z; }

// async global->LDS, 16B per lane. LDS dst is wave-uniform base + lane*16.
DEV void gload_lds16(const void* g, const void* l) {
  __builtin_amdgcn_global_load_lds(
      (const __attribute__((address_space(1))) unsigned int*)(uintptr_t)g,
      (__attribute__((address_space(3))) unsigned int*)(uint32_t)(uintptr_t)l,
      16, 0, 0);
}

// ---------------- prep (weights->bf16, mask bias) + GN stats, one dispatch -------
__global__ __launch_bounds__(256) void prep_stats(const float* __restrict__ Wq,
                                                  const float* __restrict__ Wkv,
                                                  const float* __restrict__ Wp,
                                                  const int* __restrict__ mask,
                                                  const float* __restrict__ x,
                                                  const float* __restrict__ ctx,
                                                  u16* __restrict__ wq_bf,
                                                  u16* __restrict__ wkv_bf,
                                                  u16* __restrict__ wp_bf,
                                                  float* __restrict__ mb,
                                                  float* __restrict__ stx,
                                                  float* __restrict__ stc) {
  const int bid = blockIdx.x, tid = threadIdx.x;
  if (bid < 6160) {           // ---- prep part ----
    const float* src; u16* dst; int i;
    if (bid < 1024)      { src = Wq;  dst = wq_bf;  i = bid * 256 + tid; }
    else if (bid < 5120) { src = Wkv; dst = wkv_bf; i = (bid - 1024) * 256 + tid; }
    else if (bid < 6144) { src = Wp;  dst = wp_bf;  i = (bid - 5120) * 256 + tid; }
    else {
      int j = (bid - 6144) * 256 + tid;
      mb[j] = mask[j] ? 0.f : -1e9f;
      return;
    }
    f32x4 v = ((const f32x4*)src)[i];
    u16x4 o; o[0]=f2bf(v[0]); o[1]=f2bf(v[1]); o[2]=f2bf(v[2]); o[3]=f2bf(v[3]);
    ((u16x4*)dst)[i] = o;
    return;
  }
  // ---- GN stats part (1024 blocks) ----
  const int sid = bid - 6160;
  float s = 0.f, ss = 0.f;
  float* st; int slot; float inv_n;
  if (sid < 512) {
    const int b = sid >> 5, g = sid & 31;
    const float* p = x + ((size_t)b * CC + g * 32) * SS;
    for (int it = 0; it < 32; ++it) {
      f32x4 v = *(const f32x4*)(p + it * 1024 + tid * 4);
      s  += v[0] + v[1] + v[2] + v[3];
      ss += v[0]*v[0] + v[1]*v[1] + v[2]*v[2] + v[3]*v[3];
    }
    st = stx; slot = sid; inv_n = 1.f / 32768.f;
  } else {
    const int sid2 = sid - 512;
    const int b = sid2 >> 5, g = sid2 & 31;
    const float* p = ctx + (size_t)b * SKK * CTX + g * 64;
    const int ch = tid & 63, r0 = tid >> 6;
    for (int it = 0; it < 64; ++it) {
      float v = p[(size_t)(it * 4 + r0) * CTX + ch];
      s += v; ss += v * v;
    }
    st = stc; slot = sid2; inv_n = 1.f / 16384.f;
  }
  __shared__ float red[512];
  red[tid] = s; red[256 + tid] = ss;
  __syncthreads();
  for (int o = 128; o > 0; o >>= 1) {
    if (tid < o) { red[tid] += red[tid + o]; red[256 + tid] += red[256 + tid + o]; }
    __syncthreads();
  }
  if (tid == 0) {
    float mean = red[0] * inv_n;
    float var  = red[256] * inv_n - mean * mean;
    st[slot * 2 + 0] = mean;
    st[slot * 2 + 1] = rsqrtf(var + 1e-5f);
  }
}

// ---------------- GroupNorm apply (ctx: blocks 0..8191; x-transpose: 8192..) --
__global__ __launch_bounds__(256) void gn_apply_all(const float* __restrict__ x,
                                                    const float* __restrict__ ctx,
                                                    const float* __restrict__ stx,
                                                    const float* __restrict__ stc,
                                                    const float* __restrict__ gamma_x,
                                                    const float* __restrict__ beta_x,
                                                    const float* __restrict__ gamma_c,
                                                    const float* __restrict__ beta_c,
                                                    u16* __restrict__ xnT,
                                                    u16* __restrict__ ctxn) {
  __shared__ float t[64][65];
  const int bid = blockIdx.x, tid = threadIdx.x;
  if (bid < 8192) {
    size_t i = ((size_t)bid * 256 + tid) * 4;
    int ch = (int)(i & 2047);
    int bs = (int)(i >> 11);
    int b = bs >> 8;
    int g = ch >> 6;
    float mean = stc[(b * 32 + g) * 2], rstd = stc[(b * 32 + g) * 2 + 1];
    f32x4 v  = *(const f32x4*)(ctx + i);
    f32x4 ga = *(const f32x4*)(gamma_c + ch);
    f32x4 be = *(const f32x4*)(beta_c + ch);
    u16x4 o;
    o[0] = f2bf((v[0] - mean) * rstd * ga[0] + be[0]);
    o[1] = f2bf((v[1] - mean) * rstd * ga[1] + be[1]);
    o[2] = f2bf((v[2] - mean) * rstd * ga[2] + be[2]);
    o[3] = f2bf((v[3] - mean) * rstd * ga[3] + be[3]);
    *(u16x4*)(ctxn + i) = o;
    return;
  }
  const int id2 = bid - 8192;                       // [0, 4096)
  const int b = id2 >> 8, c0 = ((id2 >> 4) & 15) * 64, s0 = (id2 & 15) * 64;
  const int j = tid & 63, i0 = tid >> 6;
  for (int it = 0; it < 16; ++it) {
    int i = it * 4 + i0;
    int c = c0 + i;
    int g = c >> 5;
    float mean = stx[(b * 32 + g) * 2], rstd = stx[(b * 32 + g) * 2 + 1];
    float v = x[((size_t)b * CC + c) * SS + s0 + j];
    t[i][j] = (v - mean) * rstd * gamma_x[c] + beta_x[c];
  }
  __syncthreads();
  for (int it = 0; it < 16; ++it) {
    int jj = it * 4 + i0;
    xnT[((size_t)b * SS + s0 + jj) * CC + c0 + j] = f2bf(t[j][jj]);
  }
}

// ---------------- m201-style GEMM core: 256x256 tile, 8 waves (2Mx4N),
// 4-slot LDS FIFO of K=32 units; two-barrier phase schedule:
//   [top]  STAGE(g+3)                       (counted prefetch, depth 3)
//   [bar]  lgkmcnt(0)+sched_barrier         (READS(g) issued last iter, drained
//   setprio(1) 32 MFMA setprio(0)            during barrier wait)
//   vmcnt(8)  [unit g+1 landed]  [bar]
//   READS(g+1)                               (issue next unit's ds_reads early)
// Bank-conflict-free: read chunk = hi ^ ((fr>>1)&3); global source pre-swizzled
// with the same involution (LDS dest stays linear per gload_lds rules).
DEV void gemm8_core(const u16* __restrict__ A, const u16* __restrict__ B,
                    int ld, int nu, u16* lds, f32x4 acc[8][4], int tid) {
  const int wid = tid >> 6, lane = tid & 63;
  const int wr = wid >> 2, wc = wid & 3;
  const int fr = lane & 15, hi = lane >> 4;
  const int rj0 = tid >> 2;
  const int ksw = (((tid & 3) ^ ((rj0 >> 1) & 3)) << 3);  // pre-swizzled src chunk
  const int ko  = ((hi ^ ((fr >> 1) & 3)) << 3);          // swizzled read slot

  auto STAGE = [&](int u) {
    int uc = u < nu ? u : nu - 1;
    int kof = (uc >> 1) * 64 + (uc & 1) * 32 + ksw;
    u16* la = lds + (u & 3) * 16384;          // A slot; B at +8192
    gload_lds16(A + (long)rj0 * ld + kof,         la + tid * 8);
    gload_lds16(A + (long)(rj0 + 128) * ld + kof, la + 4096 + tid * 8);
    gload_lds16(B + (long)rj0 * ld + kof,         la + 8192 + tid * 8);
    gload_lds16(B + (long)(rj0 + 128) * ld + kof, la + 12288 + tid * 8);
  };

  s16x8 a[8], b[4];
  auto READS = [&](int g) {
    const u16* As = lds + (g & 3) * 16384;
    const u16* Bs = As + 8192;
#pragma unroll
    for (int m = 0; m < 8; ++m) a[m] = ld8(As + (wr * 128 + m * 16 + fr) * 32 + ko);
#pragma unroll
    for (int n = 0; n < 4; ++n) b[n] = ld8(Bs + (wc * 64 + n * 16 + fr) * 32 + ko);
  };

  STAGE(0); STAGE(1); STAGE(2);               // 12 loads in flight
  asm volatile("s_waitcnt vmcnt(8)" ::: "memory");   // unit 0 landed
  __builtin_amdgcn_s_barrier();
  READS(0);

#pragma unroll 1
  for (int g = 0; g < nu; ++g) {
    STAGE(g + 3);
    __builtin_amdgcn_s_barrier();
    asm volatile("s_waitcnt lgkmcnt(0)" ::: "memory");
    __builtin_amdgcn_sched_barrier(0);        // rule #18: pin MFMA after the wait
    __builtin_amdgcn_s_setprio(1);
#pragma unroll
    for (int m = 0; m < 8; ++m)
#pragma unroll
      for (int n = 0; n < 4; ++n)
        acc[m][n] = __builtin_amdgcn_mfma_f32_16x16x32_bf16(a[m], b[n], acc[m][n], 0, 0, 0);
    __builtin_amdgcn_s_setprio(0);
    asm volatile("s_waitcnt vmcnt(8)" ::: "memory"); // unit g+1 landed; g+2,g+3 fly
    __builtin_amdgcn_s_barrier();
    if (g + 1 < nu) READS(g + 1);             // issue next unit's reads early
  }
}

// ---------------- merged Q + KV projection GEMM (384 blocks x 512 thr) ----------
// Per XCD 48 blocks: l 0..15 = KV (64 units, dispatched first), l 16..47 = Q (32).
__global__ __launch_bounds__(512) void gemm_qkv8(
    const u16* __restrict__ xnT, const u16* __restrict__ wq,
    const u16* __restrict__ ctxn, const u16* __restrict__ wkv,
    u16* __restrict__ qt, u16* __restrict__ kvt, u16* __restrict__ v2,
    const float* __restrict__ bq, const float* __restrict__ bkv) {
  __shared__ alignas(16) u16 lds[65536];      // 128 KB: 4 slots x (A 8K + B 8K) u16
  const int tid = threadIdx.x;
  const int xcd = blockIdx.x & 7, l = blockIdx.x >> 3;
  const int wid = tid >> 6, lane = tid & 63;
  const int wr = wid >> 2, wc = wid & 3;
  const int fr = lane & 15, hi = lane >> 4;

  f32x4 acc[8][4];
#pragma unroll
  for (int m = 0; m < 8; ++m)
#pragma unroll
    for (int n = 0; n < 4; ++n) acc[m][n] = zero4();

  if (l < 16) {            // ---- KV: M=256 (s'), N tile tn of 8, K=2048 ----
    const int kvid = xcd * 16 + l;
    const int bz = kvid >> 3, tn = kvid & 7;
    const u16* A = ctxn + (long)bz * SKK * CTX;
    const u16* B = wkv + (long)tn * 256 * CTX;
    gemm8_core(A, B, CTX, 64, lds, acc, tid);

    const int rowb = wr * 128 + hi * 4;                 // s' base
    const int colb = tn * 256 + wc * 64 + fr;           // o2 base
    if (tn < 4) {          // K half -> kvt (scaled)
      u16* C = kvt + (long)bz * SKK * CTX;
#pragma unroll
      for (int m = 0; m < 8; ++m)
#pragma unroll
        for (int n = 0; n < 4; ++n) {
          int col = colb + n * 16;
          float bia = bkv[col];
          f32x4 vv = acc[m][n];
#pragma unroll
          for (int i = 0; i < 4; ++i)
            C[(long)(rowb + m * 16 + i) * CTX + col] = f2bf((vv[i] + bia) * ATT_SCALE);
        }
    } else {               // V half -> v2[b][o][s'] transposed, packed 8B stores
      u16* V = v2 + (long)bz * CC * SKK;
#pragma unroll
      for (int m = 0; m < 8; ++m)
#pragma unroll
        for (int n = 0; n < 4; ++n) {
          int col = colb + n * 16;                      // 1024..2047
          float bia = bkv[col];
          f32x4 vv = acc[m][n];
          u16x4 pk;
#pragma unroll
          for (int i = 0; i < 4; ++i) pk[i] = f2bf(vv[i] + bia);
          *(u16x4*)(V + (long)(col - CC) * SKK + rowb + m * 16) = pk;
        }
    }
  } else {                 // ---- Q: 256x256 tiles, K=1024 ----
    const int q = xcd * 32 + (l - 16);
    const int bz = q >> 4, tm = (q >> 2) & 3, tn = q & 3;
    const u16* A = xnT + (long)bz * SS * CC + (long)tm * 256 * CC;
    const u16* B = wq + (long)tn * 256 * CC;
    gemm8_core(A, B, CC, 32, lds, acc, tid);

    u16* C = qt + (long)bz * SS * CC;
    const int rowb = tm * 256 + wr * 128 + hi * 4;
    const int colb = tn * 256 + wc * 64 + fr;
#pragma unroll
    for (int m = 0; m < 8; ++m)
#pragma unroll
      for (int n = 0; n < 4; ++n) {
        int col = colb + n * 16;
        float bia = bq[col];
        f32x4 vv = acc[m][n];
#pragma unroll
        for (int i = 0; i < 4; ++i)
          C[(long)(rowb + m * 16 + i) * CC + col] = f2bf((vv[i] + bia) * ATT_SCALE);
      }
  }
}

// ---------------- proj GEMM + bias + fp32 residual (256 blocks x 512 thr) --------
__global__ __launch_bounds__(512) void gemm_proj8(
    const u16* __restrict__ wp, const u16* __restrict__ at,
    float* __restrict__ out, const float* __restrict__ bp,
    const float* __restrict__ x) {
  __shared__ alignas(16) u16 lds[65536];
  const int tid = threadIdx.x;
  const int v = (blockIdx.x & 7) * 32 + (blockIdx.x >> 3);
  const int bz = v >> 4, tm = (v >> 2) & 3, tn = v & 3;
  const int wid = tid >> 6, lane = tid & 63;
  const int wr = wid >> 2, wc = wid & 3;
  const int fr = lane & 15, hi = lane >> 4;

  f32x4 acc[8][4];
#pragma unroll
  for (int m = 0; m < 8; ++m)
#pragma unroll
    for (int n = 0; n < 4; ++n) acc[m][n] = zero4();

  const u16* A = wp + (long)tm * 256 * CC;                       // rows = o
  const u16* B = at + (long)bz * SS * CC + (long)tn * 256 * CC;  // rows = s
  gemm8_core(A, B, CC, 32, lds, acc, tid);

  float* C = out + (long)bz * CC * SS;
  const float* R = x + (long)bz * CC * SS;
  const int rowb = tm * 256 + wr * 128 + hi * 4;   // o
  const int colb = tn * 256 + wc * 64 + fr;        // s
#pragma unroll
  for (int m = 0; m < 8; ++m)
#pragma unroll
    for (int n = 0; n < 4; ++n) {
      int col = colb + n * 16;
      f32x4 vv = acc[m][n];
#pragma unroll
      for (int i = 0; i < 4; ++i) {
        int row = rowb + m * 16 + i;
        long idx = (long)row * SS + col;
        C[idx] = R[idx] + vv[i] + bp[row];
      }
    }
}

// ---------------- fused attention (LDS-staged K/V, XCD chunk swizzle) -------------
__global__ __launch_bounds__(256) void attn_fused(const u16* __restrict__ qt,
                                                  const u16* __restrict__ kvt,
                                                  const u16* __restrict__ v2,
                                                  const float* __restrict__ mbias,
                                                  u16* __restrict__ at) {
  __shared__ alignas(16) u16 k_lds[256 * 64];   // 32KB K, later P (8KB/wave)
  __shared__ alignas(16) u16 v_lds[64 * 256];   // 32KB V
  const int orig = blockIdx.x + 16 * blockIdx.y + 256 * blockIdx.z;
  const int v = (orig & 7) * 512 + (orig >> 3);
  const int bb = v >> 8, h = (v >> 4) & 15, t0 = (v & 15) * 64;

  const int tid = threadIdx.x, wid = tid >> 6, lane = tid & 63;
  const int fr = lane & 15, hi = lane >> 4;
  const int sw = fr & 7;

#pragma unroll
  for (int it = 0; it < 8; ++it) {
    int lin = (wid * 8 + it) * 1024 + lane * 16;      // byte offset in LDS
    int kr = lin >> 7, kc = (lin >> 4) & 7;
    gload_lds16(kvt + ((long)bb * SKK + kr) * CTX + h * HD + ((kc ^ (kr & 7)) << 3),
                (const char*)k_lds + (wid * 8 + it) * 1024);
    int vr = lin >> 9, vc = (lin >> 4) & 31;
    gload_lds16(v2 + ((long)bb * CC + h * HD + vr) * SKK + ((vc ^ (vr & 7)) << 3),
                (const char*)v_lds + (wid * 8 + it) * 1024);
  }

  const u16* qp = qt + ((long)bb * SS + t0 + wid * 16 + fr) * CC + h * HD + hi * 8;
  s16x8 aq0 = ld8(qp), aq1 = ld8(qp + 32);

  __syncthreads();

  f32x4 sc[16];
#pragma unroll
  for (int nf = 0; nf < 16; ++nf) {
    const u16* krow = k_lds + (nf * 16 + fr) * 64;
    s16x8 kb0 = ld8(krow + (((hi) ^ sw) << 3));
    s16x8 kb1 = ld8(krow + (((4 + hi) ^ sw) << 3));
    f32x4 z = zero4();
    z = __builtin_amdgcn_mfma_f32_16x16x32_bf16(aq0, kb0, z, 0, 0, 0);
    sc[nf] = __builtin_amdgcn_mfma_f32_16x16x32_bf16(aq1, kb1, z, 0, 0, 0);
  }

  __syncthreads();   // all waves done reading K -> safe to overwrite with P

  const float* mb = mbias + bb * SKK + fr;
#pragma unroll
  for (int nf = 0; nf < 16; ++nf) sc[nf] = sc[nf] + mb[nf * 16];

#pragma unroll
  for (int i = 0; i < 4; ++i) {
    float m = sc[0][i];
#pragma unroll
    for (int nf = 1; nf < 16; ++nf) m = fmaxf(m, sc[nf][i]);
#pragma unroll
    for (int d = 1; d < 16; d <<= 1) m = fmaxf(m, __shfl_xor(m, d));
    float s = 0.f;
#pragma unroll
    for (int nf = 0; nf < 16; ++nf) {
      float e = __expf(sc[nf][i] - m);
      sc[nf][i] = e; s += e;
    }
#pragma unroll
    for (int d = 1; d < 16; d <<= 1) s += __shfl_xor(s, d);
    float inv = 1.0f / s;
#pragma unroll
    for (int nf = 0; nf < 16; ++nf) sc[nf][i] *= inv;
  }

  u16* p_base = k_lds + wid * 4096;
#pragma unroll
  for (int nf = 0; nf < 16; ++nf) {
    int c = 2 * nf + (fr >> 3);
#pragma unroll
    for (int i = 0; i < 4; ++i) {
      int t = 4 * hi + i;
      p_base[t * 256 + (((c ^ (t & 7)) << 3)) + sw] = f2bf(sc[nf][i]);
    }
  }

  f32x4 ov[4];
#pragma unroll
  for (int n = 0; n < 4; ++n) ov[n] = zero4();
#pragma unroll
  for (int kk = 0; kk < 8; ++kk) {
    int c = 4 * kk + hi;
    s16x8 pa = ld8(p_base + fr * 256 + ((c ^ sw) << 3));
#pragma unroll
    for (int n = 0; n < 4; ++n) {
      int o = n * 16 + fr;
      s16x8 vb = ld8(v_lds + o * 256 + ((c ^ sw) << 3));
      ov[n] = __builtin_amdgcn_mfma_f32_16x16x32_bf16(pa, vb, ov[n], 0, 0, 0);
    }
  }

  const int rbase = hi * 4;
  u16* po = at + ((long)bb * SS + t0 + wid * 16 + rbase) * CC + h * HD + fr;
#pragma unroll
  for (int n = 0; n < 4; ++n)
#pragma unroll
    for (int i = 0; i < 4; ++i) po[(long)i * CC + n * 16] = f2bf(ov[n][i]);
}

// ---------------- launcher ----------------
extern "C" void kernel_launch(void* const* d_in, const int* in_sizes, int n_in,
                              void* d_out, int out_size, void* d_ws, size_t ws_size,
                              hipStream_t stream) {
  const float* x       = (const float*)d_in[0];
  const float* context = (const float*)d_in[1];
  const int*   mask    = (const int*)d_in[2];
  const float* gamma_x = (const float*)d_in[3];
  const float* beta_x  = (const float*)d_in[4];
  const float* gamma_c = (const float*)d_in[5];
  const float* beta_c  = (const float*)d_in[6];
  const float* Wq      = (const float*)d_in[7];
  const float* bq      = (const float*)d_in[8];
  const float* Wkv     = (const float*)d_in[9];
  const float* bkv     = (const float*)d_in[10];
  const float* Wp      = (const float*)d_in[11];
  const float* bp      = (const float*)d_in[12];
  float* out = (float*)d_out;

  char* w = (char*)d_ws;
  size_t off = 0;
  u16* wq_bf  = (u16*)(w + off); off += (size_t)CC * CC * 2;
  u16* wkv_bf = (u16*)(w + off); off += (size_t)CTX * CTX * 2;
  u16* wp_bf  = (u16*)(w + off); off += (size_t)CC * CC * 2;
  u16* xnT    = (u16*)(w + off); off += (size_t)BB * SS * CC * 2;
  u16* ctxn   = (u16*)(w + off); off += (size_t)BB * SKK * CTX * 2;
  u16* qt     = (u16*)(w + off); off += (size_t)BB * SS * CC * 2;
  u16* kvt    = (u16*)(w + off); off += (size_t)BB * SKK * CTX * 2;
  u16* v2     = (u16*)(w + off); off += (size_t)BB * CC * SKK * 2;
  u16* at     = (u16*)(w + off); off += (size_t)BB * SS * CC * 2;
  float* mb   = (float*)(w + off); off += (size_t)BB * SKK * 4;
  float* stx  = (float*)(w + off); off += (size_t)BB * NG * 2 * 4;
  float* stc  = (float*)(w + off); off += (size_t)BB * NG * 2 * 4;
  (void)ws_size; (void)in_sizes; (void)n_in; (void)out_size;

  prep_stats<<<7184, 256, 0, stream>>>(Wq, Wkv, Wp, mask, x, context,
                                       wq_bf, wkv_bf, wp_bf, mb, stx, stc);

  gn_apply_all<<<12288, 256, 0, stream>>>(x, context, stx, stc,
                                          gamma_x, beta_x, gamma_c, beta_c,
                                          xnT, ctxn);

  gemm_qkv8<<<384, 512, 0, stream>>>(xnT, wq_bf, ctxn, wkv_bf, qt, kvt, v2, bq, bkv);

  attn_fused<<<dim3(16, NH, BB), 256, 0, stream>>>(qt, kvt, v2, mb, at);

  gemm_proj8<<<256, 512, 0, stream>>>(wp_bf, at, out, bp, x);
}